// Round 1
// baseline (11770.283 us; speedup 1.0000x reference)
//
#include <hip/hip_runtime.h>
#include <stdint.h>

// SoftNMS (gaussian, sigma=0.5, score_thr=0.001) over N=4096 boxes, 2 classes.
// Sequential selection chain -> single workgroup, state in registers.
// Numerics: match numpy float32 op-for-op (block FMA contraction with __f*_rn,
// IEEE division, precise expf) because outputs are a selection *permutation* —
// any order flip is a huge absmax error.

#define N_BOXES 4096
#define T 256            // threads (4 waves)
#define E (N_BOXES / T)  // 16 boxes per thread, held in registers
#define SCORE_THR 0.001f

typedef unsigned long long u64;

__launch_bounds__(T, 1)
__global__ void softnms_kernel(const float* __restrict__ boxes,
                               const float* __restrict__ scores,
                               const int* __restrict__ labels,
                               float* __restrict__ out) {
    __shared__ u64   red[2][T / 64];   // per-wave argmax slots, double-buffered
    __shared__ float wboxS[2][4];      // winner box broadcast

    const int tid  = threadIdx.x;
    const int lane = tid & 63;
    const int wid  = tid >> 6;

    float x1r[E], y1r[E], x2r[E], y2r[E], ar[E], sc[E];
    int   lb[E];
    uint32_t low[E];

    #pragma unroll
    for (int j = 0; j < E; ++j) {
        int g = tid + T * j;
        float4 b = reinterpret_cast<const float4*>(boxes)[g];
        x1r[j] = b.x; y1r[j] = b.y; x2r[j] = b.z; y2r[j] = b.w;
        ar[j]  = __fmul_rn(__fsub_rn(b.z, b.x), __fsub_rn(b.w, b.y));
        sc[j]  = scores[g];
        lb[j]  = labels[g];
        // key low bits: (4095-g)<<16 | label  -> ties (impossible for distinct
        // float scores) break toward smaller index, matching jnp.argmax.
        low[j] = ((uint32_t)(4095 - g) << 16) | (uint32_t)(lb[j] & 0xFFFF);
    }

    float* out_boxes  = out;
    float* out_scores = out + N_BOXES * 4;
    float* out_labels = out + N_BOXES * 5;

    int buf  = 0;
    int iter = 0;
    for (; iter < N_BOXES; ++iter) {
        // ---- masked argmax: dead score = 0.0f (< SCORE_THR) ----
        u64 best = 0;
        #pragma unroll
        for (int j = 0; j < E; ++j) {
            u64 k = ((u64)__float_as_uint(sc[j]) << 32) | (u64)low[j];
            best = (k > best) ? k : best;
        }
        u64 mykey = best;  // pre-reduce local max: identifies the owner thread
        #pragma unroll
        for (int off = 32; off >= 1; off >>= 1) {
            u64 o = __shfl_xor(best, off, 64);
            best = (o > best) ? o : best;
        }
        if (lane == 0) red[buf][wid] = best;
        __syncthreads();
        u64 w = red[buf][0];
        #pragma unroll
        for (int k = 1; k < T / 64; ++k) {
            u64 o = red[buf][k];
            w = (o > w) ? o : w;
        }
        float wscore = __uint_as_float((uint32_t)(w >> 32));
        if (wscore < SCORE_THR) break;  // no active boxes left (uniform)

        int widx = 4095 - (int)((w >> 16) & 0xFFFF);
        int wlab = (int)(w & 0xFFFF);

        // ---- owner (unique key match) publishes winner coords ----
        if (mykey == w) {
            int jj = widx >> 8;  // g = tid + 256*j  ->  j = g >> 8
            float ox1 = x1r[0], oy1 = y1r[0], ox2 = x2r[0], oy2 = y2r[0];
            #pragma unroll
            for (int j = 1; j < E; ++j) {
                if (jj == j) { ox1 = x1r[j]; oy1 = y1r[j]; ox2 = x2r[j]; oy2 = y2r[j]; }
            }
            wboxS[buf][0] = ox1; wboxS[buf][1] = oy1;
            wboxS[buf][2] = ox2; wboxS[buf][3] = oy2;
        }
        __syncthreads();
        float wx1 = wboxS[buf][0], wy1 = wboxS[buf][1];
        float wx2 = wboxS[buf][2], wy2 = wboxS[buf][3];
        float warea = __fmul_rn(__fsub_rn(wx2, wx1), __fsub_rn(wy2, wy1));

        if (tid == 0) {
            out_boxes[iter * 4 + 0] = wx1;
            out_boxes[iter * 4 + 1] = wy1;
            out_boxes[iter * 4 + 2] = wx2;
            out_boxes[iter * 4 + 3] = wy2;
            out_scores[iter] = wscore;      // cur[i] BEFORE this step's decay
            out_labels[iter] = (float)wlab;
        }

        // ---- decay same-class boxes; deactivate winner + sub-threshold ----
        #pragma unroll
        for (int j = 0; j < E; ++j) {
            if (lb[j] == wlab) {
                float ix1 = fmaxf(wx1, x1r[j]);
                float iy1 = fmaxf(wy1, y1r[j]);
                float ix2 = fminf(wx2, x2r[j]);
                float iy2 = fminf(wy2, y2r[j]);
                float iw = fmaxf(__fsub_rn(ix2, ix1), 0.0f);
                float ih = fmaxf(__fsub_rn(iy2, iy1), 0.0f);
                float inter = __fmul_rn(iw, ih);
                float denom = __fadd_rn(__fsub_rn(__fadd_rn(warea, ar[j]), inter), 1e-8f);
                float iou   = inter / denom;              // IEEE-correct div
                float t2    = __fmul_rn(iou, iou);
                float decay = expf(__fmul_rn(-2.0f, t2)); // exp(-(iou^2)/0.5)
                float ns    = __fmul_rn(sc[j], decay);
                sc[j] = (ns >= SCORE_THR) ? ns : 0.0f;    // 0.0f == inactive
            }
            int g = tid + T * j;
            if (g == widx) sc[j] = 0.0f;
        }
        buf ^= 1;
    }

    // ---- pad the invalid tail: boxes 0, score 0, label -1 ----
    for (int k = iter + tid; k < N_BOXES; k += T) {
        out_boxes[k * 4 + 0] = 0.0f;
        out_boxes[k * 4 + 1] = 0.0f;
        out_boxes[k * 4 + 2] = 0.0f;
        out_boxes[k * 4 + 3] = 0.0f;
        out_scores[k] = 0.0f;
        out_labels[k] = -1.0f;
    }
}

extern "C" void kernel_launch(void* const* d_in, const int* in_sizes, int n_in,
                              void* d_out, int out_size, void* d_ws, size_t ws_size,
                              hipStream_t stream) {
    const float* boxes  = (const float*)d_in[0];
    const float* scores = (const float*)d_in[1];
    const int*   labels = (const int*)d_in[2];
    float* out = (float*)d_out;
    (void)in_sizes; (void)n_in; (void)out_size; (void)d_ws; (void)ws_size;
    softnms_kernel<<<1, T, 0, stream>>>(boxes, scores, labels, out);
}

// Round 2
// 5851.986 us; speedup vs baseline: 2.0113x; 2.0113x over previous
//
#include <hip/hip_runtime.h>
#include <stdint.h>

// SoftNMS (gaussian, sigma=0.5, thr=0.001), N=4096, 2 classes.
// R2: classes are independent decay chains whose selection scores are
// non-increasing -> run one block per class in parallel (2048-ish steps each,
// half the per-step work), then merge the two strictly-descending key lists
// by rank (binary search) in a second kernel. Key = score_bits<<32 |
// (4095-idx)<<16 gives exactly jnp.argmax's smaller-index tie-break, both in
// the per-class argmax and in the merge comparator.
// All float ops bitwise-identical to the round-1 kernel (absmax 0.0).

#define N_BOXES 4096
#define T 256
#define CAP 16            // slots/thread capacity (worst case: one class owns all)
#define SCORE_THR 0.001f

typedef unsigned long long u64;
typedef uint32_t u32;

__device__ __forceinline__ u64 kmax(u64 a, u64 b) { return a > b ? a : b; }

// workspace layout (196616 bytes)
#define WS_KEY(ws, c)  ((u64*)((char*)(ws) + (size_t)(c) * 32768))
#define WS_BOX(ws, c)  ((float4*)((char*)(ws) + 65536 + (size_t)(c) * 65536))
#define WS_CNT(ws)     ((int*)((char*)(ws) + 196608))

__launch_bounds__(T, 1)
__global__ void softnms_class(const float* __restrict__ boxes,
                              const float* __restrict__ scores,
                              const int* __restrict__ labels,
                              void* __restrict__ ws) {
    const int cls  = blockIdx.x;
    const int tid  = threadIdx.x;
    const int lane = tid & 63;
    const int wid  = tid >> 6;

    __shared__ u64 maskw[64];      // class-membership bitmask, 64 bits/word
    __shared__ u32 wordpref[64];   // inclusive prefix of popcounts
    __shared__ u64 red[2][4];      // cross-wave argmax slots, double-buffered

    // ---- phase 0a: build membership bitmask ----
    for (int base = 0; base < N_BOXES; base += T) {
        u64 bal = __ballot(labels[base + tid] == cls);
        if (lane == 0) maskw[(base >> 6) + wid] = bal;
    }
    __syncthreads();
    if (wid == 0) {
        u32 v = (u32)__popcll(maskw[lane]);
        #pragma unroll
        for (int d = 1; d < 64; d <<= 1) {
            u32 o = __shfl_up(v, d, 64);
            if (lane >= d) v += o;
        }
        wordpref[lane] = v;
    }
    __syncthreads();
    const int cnt = (int)wordpref[63];

    // ---- phase 0b: rank-select my slots (r = tid + 256*j), load to regs ----
    float x1r[CAP], y1r[CAP], x2r[CAP], y2r[CAP], ar[CAP];
    u64 key[CAP];
    const float4* boxes4 = reinterpret_cast<const float4*>(boxes);
    #pragma unroll
    for (int j = 0; j < CAP; ++j) {
        key[j] = 0;
        x1r[j] = 0.0f; y1r[j] = 0.0f; x2r[j] = 0.0f; y2r[j] = 0.0f; ar[j] = 0.0f;
        int r = tid + T * j;
        if (r < cnt) {
            // smallest word W with wordpref[W] > r
            int lo = 0, hi = 63;
            while (lo < hi) { int mid = (lo + hi) >> 1; if (wordpref[mid] > (u32)r) hi = mid; else lo = mid + 1; }
            int W = lo;
            u32 rb = (W == 0) ? 0u : wordpref[W - 1];
            u32 t = (u32)r - rb;
            u64 x = maskw[W];
            int pos = 0;
            u32 c;
            c = (u32)__popcll(x & 0xFFFFFFFFull); if (t >= c) { pos += 32; t -= c; x >>= 32; }
            c = (u32)__popcll(x & 0xFFFFull);     if (t >= c) { pos += 16; t -= c; x >>= 16; }
            c = (u32)__popcll(x & 0xFFull);       if (t >= c) { pos += 8;  t -= c; x >>= 8; }
            c = (u32)__popcll(x & 0xFull);        if (t >= c) { pos += 4;  t -= c; x >>= 4; }
            c = (u32)__popcll(x & 0x3ull);        if (t >= c) { pos += 2;  t -= c; x >>= 2; }
            c = (u32)__popcll(x & 0x1ull);        if (t >= c) { pos += 1; }
            int g = W * 64 + pos;
            float4 b = boxes4[g];
            x1r[j] = b.x; y1r[j] = b.y; x2r[j] = b.z; y2r[j] = b.w;
            ar[j]  = __fmul_rn(__fsub_rn(b.z, b.x), __fsub_rn(b.w, b.y));
            float s = scores[g];
            key[j] = ((u64)__float_as_uint(s) << 32) | ((u64)(u32)(4095 - g) << 16);
        }
    }

    // ---- phase 1: sequential soft-NMS chain over this class ----
    u64*    okey = WS_KEY(ws, cls);
    float4* obox = WS_BOX(ws, cls);
    int mcnt = 0;
    int buf  = 0;
    for (int step = 0; step < cnt; ++step) {
        // local tree max over 16 register keys (depth 4)
        u64 t0[CAP];
        #pragma unroll
        for (int j = 0; j < CAP; ++j) t0[j] = key[j];
        #pragma unroll
        for (int s = CAP >> 1; s >= 1; s >>= 1) {
            #pragma unroll
            for (int i = 0; i < s; ++i) t0[i] = kmax(t0[i], t0[i + s]);
        }
        u64 best = t0[0];
        #pragma unroll
        for (int off = 32; off >= 1; off >>= 1)
            best = kmax(best, __shfl_xor(best, off, 64));
        if (lane == 0) red[buf][wid] = best;
        __syncthreads();
        u64 w = kmax(kmax(red[buf][0], red[buf][1]), kmax(red[buf][2], red[buf][3]));
        float wscore = __uint_as_float((u32)(w >> 32));
        if (wscore < SCORE_THR) break;   // uniform

        int g = 4095 - (int)(((u32)w) >> 16);
        float4 wb = boxes4[g];           // all lanes same addr -> broadcast
        float wx1 = wb.x, wy1 = wb.y, wx2 = wb.z, wy2 = wb.w;
        float warea = __fmul_rn(__fsub_rn(wx2, wx1), __fsub_rn(wy2, wy1));
        if (tid == 0) { okey[mcnt] = w; obox[mcnt] = wb; }
        mcnt++;

        // decay all live same-class boxes (winner -> dead)
        #pragma unroll
        for (int j = 0; j < CAP; ++j) {
            int r = tid + T * j;
            if (r < cnt) {               // wave-uniform skip for j >= jmax
                u64 kj = key[j];
                if (kj != 0) {
                    if (kj == w) {
                        key[j] = 0;
                    } else {
                        float sc    = __uint_as_float((u32)(kj >> 32));
                        float ix1   = fmaxf(wx1, x1r[j]);
                        float iy1   = fmaxf(wy1, y1r[j]);
                        float ix2   = fminf(wx2, x2r[j]);
                        float iy2   = fminf(wy2, y2r[j]);
                        float iw    = fmaxf(__fsub_rn(ix2, ix1), 0.0f);
                        float ih    = fmaxf(__fsub_rn(iy2, iy1), 0.0f);
                        float inter = __fmul_rn(iw, ih);
                        float denom = __fadd_rn(__fsub_rn(__fadd_rn(warea, ar[j]), inter), 1e-8f);
                        float iou   = inter / denom;                // IEEE div
                        float t2    = __fmul_rn(iou, iou);
                        float decay = expf(__fmul_rn(-2.0f, t2));   // exp(-iou^2/0.5)
                        float ns    = __fmul_rn(sc, decay);
                        key[j] = (ns >= SCORE_THR)
                                   ? (((u64)__float_as_uint(ns) << 32) | (kj & 0xFFFFFFFFull))
                                   : 0;
                    }
                }
            }
        }
        buf ^= 1;
    }
    if (tid == 0) WS_CNT(ws)[cls] = mcnt;
}

// merge the two strictly-descending key lists by rank; pad the tail
__global__ void softnms_merge(void* __restrict__ ws, float* __restrict__ out) {
    int k = blockIdx.x * blockDim.x + threadIdx.x;   // 0..4095
    const u64*    keyA = WS_KEY(ws, 0);
    const u64*    keyB = WS_KEY(ws, 1);
    const float4* boxA = WS_BOX(ws, 0);
    const float4* boxB = WS_BOX(ws, 1);
    const int mA = WS_CNT(ws)[0];
    const int mB = WS_CNT(ws)[1];

    float* ob = out;
    float* os = out + N_BOXES * 4;
    float* ol = out + N_BOXES * 5;

    if (k < mA) {
        u64 x = keyA[k];
        int lo = 0, hi = mB;
        while (lo < hi) { int mid = (lo + hi) >> 1; if (keyB[mid] > x) lo = mid + 1; else hi = mid; }
        int pos = k + lo;
        float4 b = boxA[k];
        ob[pos * 4 + 0] = b.x; ob[pos * 4 + 1] = b.y;
        ob[pos * 4 + 2] = b.z; ob[pos * 4 + 3] = b.w;
        os[pos] = __uint_as_float((u32)(x >> 32));
        ol[pos] = 0.0f;
    } else if (k < mA + mB) {
        int i = k - mA;
        u64 x = keyB[i];
        int lo = 0, hi = mA;
        while (lo < hi) { int mid = (lo + hi) >> 1; if (keyA[mid] > x) lo = mid + 1; else hi = mid; }
        int pos = i + lo;
        float4 b = boxB[i];
        ob[pos * 4 + 0] = b.x; ob[pos * 4 + 1] = b.y;
        ob[pos * 4 + 2] = b.z; ob[pos * 4 + 3] = b.w;
        os[pos] = __uint_as_float((u32)(x >> 32));
        ol[pos] = 1.0f;
    } else {
        ob[k * 4 + 0] = 0.0f; ob[k * 4 + 1] = 0.0f;
        ob[k * 4 + 2] = 0.0f; ob[k * 4 + 3] = 0.0f;
        os[k] = 0.0f;
        ol[k] = -1.0f;
    }
}

extern "C" void kernel_launch(void* const* d_in, const int* in_sizes, int n_in,
                              void* d_out, int out_size, void* d_ws, size_t ws_size,
                              hipStream_t stream) {
    const float* boxes  = (const float*)d_in[0];
    const float* scores = (const float*)d_in[1];
    const int*   labels = (const int*)d_in[2];
    float* out = (float*)d_out;
    (void)in_sizes; (void)n_in; (void)out_size; (void)ws_size;
    softnms_class<<<2, T, 0, stream>>>(boxes, scores, labels, d_ws);
    softnms_merge<<<N_BOXES / T, T, 0, stream>>>(d_ws, out);
}

// Round 3
// 5562.452 us; speedup vs baseline: 2.1160x; 1.0521x over previous
//
#include <hip/hip_runtime.h>
#include <stdint.h>

// SoftNMS (gaussian, sigma=0.5, thr=0.001), N=4096, 2 classes.
// R3: per-step dependency chain was latency-bound (2.9us/step, invariant to
// work halving). Changes vs R2:
//  - DPP-based wave max (VALU latency) replaces 6x u64 __shfl_xor (12
//    dependent ds_bpermute @ ~120cyc). Exact two-phase: u32 max of score
//    bits, then masked u32 max of low bits (4095-g | r) for tie-breaks.
//  - winner box fetched from LDS by slot-rank r (encoded in key low 16 bits)
//    instead of a ~200-900cyc global L2 load.
//  - decay loop fused with next step's local-max accumulation.
// Float ops bitwise-identical to R1/R2 (absmax 0.0).

#define N_BOXES 4096
#define T 256
#define CAP 16            // slots/thread capacity (worst case: one class owns all)
#define BOXCAP 3072       // LDS box cache capacity (48KB); fallback to global
#define SCORE_THR 0.001f

typedef unsigned long long u64;
typedef uint32_t u32;

__device__ __forceinline__ u64 kmax(u64 a, u64 b) { return a > b ? a : b; }

// LLVM gfx9 wave64 reduction sequence; identity 0, inputs non-negative.
__device__ __forceinline__ int wave_max_nonneg(int v) {
    v = max(v, __builtin_amdgcn_update_dpp(0, v, 0x111, 0xf, 0xf, false)); // row_shr:1
    v = max(v, __builtin_amdgcn_update_dpp(0, v, 0x112, 0xf, 0xf, false)); // row_shr:2
    v = max(v, __builtin_amdgcn_update_dpp(0, v, 0x114, 0xf, 0xf, false)); // row_shr:4
    v = max(v, __builtin_amdgcn_update_dpp(0, v, 0x118, 0xf, 0xf, false)); // row_shr:8
    v = max(v, __builtin_amdgcn_update_dpp(0, v, 0x142, 0xa, 0xf, false)); // row_bcast:15 -> rows 1,3
    v = max(v, __builtin_amdgcn_update_dpp(0, v, 0x143, 0xc, 0xf, false)); // row_bcast:31 -> rows 2,3
    return __builtin_amdgcn_readlane(v, 63);
}

// workspace layout (196616 bytes)
#define WS_KEY(ws, c)  ((u64*)((char*)(ws) + (size_t)(c) * 32768))
#define WS_BOX(ws, c)  ((float4*)((char*)(ws) + 65536 + (size_t)(c) * 65536))
#define WS_CNT(ws)     ((int*)((char*)(ws) + 196608))

__launch_bounds__(T, 1)
__global__ void softnms_class(const float* __restrict__ boxes,
                              const float* __restrict__ scores,
                              const int* __restrict__ labels,
                              void* __restrict__ ws) {
    const int cls  = blockIdx.x;
    const int tid  = threadIdx.x;
    const int lane = tid & 63;
    const int wid  = tid >> 6;

    __shared__ u64   maskw[64];      // class-membership bitmask
    __shared__ u32   wordpref[64];   // inclusive prefix of popcounts
    __shared__ u64   red[2][4];      // cross-wave argmax slots, double-buffered
    __shared__ float4 box_lds[BOXCAP];

    // ---- phase 0a: membership bitmask + popcount prefix ----
    for (int base = 0; base < N_BOXES; base += T) {
        u64 bal = __ballot(labels[base + tid] == cls);
        if (lane == 0) maskw[(base >> 6) + wid] = bal;
    }
    __syncthreads();
    if (wid == 0) {
        u32 v = (u32)__popcll(maskw[lane]);
        #pragma unroll
        for (int d = 1; d < 64; d <<= 1) {
            u32 o = __shfl_up(v, d, 64);
            if (lane >= d) v += o;
        }
        wordpref[lane] = v;
    }
    __syncthreads();
    const int cnt = (int)wordpref[63];

    // ---- phase 0b: rank-select my slots (r = tid + 256*j) -> regs + LDS ----
    float x1r[CAP], y1r[CAP], x2r[CAP], y2r[CAP], ar[CAP];
    u64 key[CAP];
    const float4* boxes4 = reinterpret_cast<const float4*>(boxes);
    #pragma unroll
    for (int j = 0; j < CAP; ++j) {
        key[j] = 0;
        x1r[j] = 0.0f; y1r[j] = 0.0f; x2r[j] = 0.0f; y2r[j] = 0.0f; ar[j] = 0.0f;
        int r = tid + T * j;
        if (r < cnt) {
            int lo = 0, hi = 63;   // smallest word W with wordpref[W] > r
            while (lo < hi) { int mid = (lo + hi) >> 1; if (wordpref[mid] > (u32)r) hi = mid; else lo = mid + 1; }
            int W = lo;
            u32 rb = (W == 0) ? 0u : wordpref[W - 1];
            u32 t = (u32)r - rb;
            u64 x = maskw[W];
            int pos = 0;
            u32 c;
            c = (u32)__popcll(x & 0xFFFFFFFFull); if (t >= c) { pos += 32; t -= c; x >>= 32; }
            c = (u32)__popcll(x & 0xFFFFull);     if (t >= c) { pos += 16; t -= c; x >>= 16; }
            c = (u32)__popcll(x & 0xFFull);       if (t >= c) { pos += 8;  t -= c; x >>= 8; }
            c = (u32)__popcll(x & 0xFull);        if (t >= c) { pos += 4;  t -= c; x >>= 4; }
            c = (u32)__popcll(x & 0x3ull);        if (t >= c) { pos += 2;  t -= c; x >>= 2; }
            c = (u32)__popcll(x & 0x1ull);        if (t >= c) { pos += 1; }
            int g = W * 64 + pos;
            float4 b = boxes4[g];
            x1r[j] = b.x; y1r[j] = b.y; x2r[j] = b.z; y2r[j] = b.w;
            ar[j]  = __fmul_rn(__fsub_rn(b.z, b.x), __fsub_rn(b.w, b.y));
            float s = scores[g];
            // key: score<<32 | (4095-g)<<16 | r   (g: argmax tie-break; r: slot)
            key[j] = ((u64)__float_as_uint(s) << 32)
                   | ((u64)(u32)(4095 - g) << 16) | (u64)(u32)r;
            if (r < BOXCAP) box_lds[r] = b;
        }
    }
    __syncthreads();

    // ---- phase 1: sequential soft-NMS chain over this class ----
    u64*    okey = WS_KEY(ws, cls);
    float4* obox = WS_BOX(ws, cls);
    const bool use_lds = (cnt <= BOXCAP);
    int mcnt = 0;
    int buf  = 0;

    u64 lbest = 0;
    #pragma unroll
    for (int j = 0; j < CAP; ++j) lbest = kmax(lbest, key[j]);

    for (int step = 0; step < cnt; ++step) {
        // exact u64 wave max, two-phase DPP (score bits, then tie-break bits)
        int hi   = (int)(u32)(lbest >> 32);
        int hmax = wave_max_nonneg(hi);
        int lom  = (hi == hmax) ? (int)(u32)lbest : 0;
        int lmax = wave_max_nonneg(lom);
        u64 wbest = ((u64)(u32)hmax << 32) | (u64)(u32)lmax;
        if (lane == 0) red[buf][wid] = wbest;
        __syncthreads();
        u64 w = kmax(kmax(red[buf][0], red[buf][1]), kmax(red[buf][2], red[buf][3]));
        float wscore = __uint_as_float((u32)(w >> 32));
        if (wscore < SCORE_THR) break;   // uniform

        int r = (int)(w & 0xFFFF);
        float4 wb;
        if (use_lds) {
            wb = box_lds[r];                               // broadcast ds_read
        } else {
            wb = boxes4[4095 - (int)((w >> 16) & 0xFFFF)]; // fallback
        }
        float wx1 = wb.x, wy1 = wb.y, wx2 = wb.z, wy2 = wb.w;
        float warea = __fmul_rn(__fsub_rn(wx2, wx1), __fsub_rn(wy2, wy1));
        if (tid == 0) { okey[mcnt] = w; obox[mcnt] = wb; }
        mcnt++;

        // decay all live boxes; fused accumulation of next step's local max
        u64 nb = 0;
        #pragma unroll
        for (int j = 0; j < CAP; ++j) {
            int rr = tid + T * j;
            if (rr < cnt) {
                u64 kj = key[j];
                if (kj != 0) {
                    if (kj == w) {
                        key[j] = 0;
                    } else {
                        float sc    = __uint_as_float((u32)(kj >> 32));
                        float ix1   = fmaxf(wx1, x1r[j]);
                        float iy1   = fmaxf(wy1, y1r[j]);
                        float ix2   = fminf(wx2, x2r[j]);
                        float iy2   = fminf(wy2, y2r[j]);
                        float iw    = fmaxf(__fsub_rn(ix2, ix1), 0.0f);
                        float ih    = fmaxf(__fsub_rn(iy2, iy1), 0.0f);
                        float inter = __fmul_rn(iw, ih);
                        float denom = __fadd_rn(__fsub_rn(__fadd_rn(warea, ar[j]), inter), 1e-8f);
                        float iou   = inter / denom;                // IEEE div
                        float t2    = __fmul_rn(iou, iou);
                        float decay = expf(__fmul_rn(-2.0f, t2));   // exp(-iou^2/0.5)
                        float ns    = __fmul_rn(sc, decay);
                        key[j] = (ns >= SCORE_THR)
                                   ? (((u64)__float_as_uint(ns) << 32) | (kj & 0xFFFFFFFFull))
                                   : 0;
                    }
                }
                nb = kmax(nb, key[j]);
            }
        }
        lbest = nb;
        buf ^= 1;
    }
    if (tid == 0) WS_CNT(ws)[cls] = mcnt;
}

// merge the two strictly-descending key lists by rank; pad the tail
__global__ void softnms_merge(void* __restrict__ ws, float* __restrict__ out) {
    int k = blockIdx.x * blockDim.x + threadIdx.x;   // 0..4095
    const u64*    keyA = WS_KEY(ws, 0);
    const u64*    keyB = WS_KEY(ws, 1);
    const float4* boxA = WS_BOX(ws, 0);
    const float4* boxB = WS_BOX(ws, 1);
    const int mA = WS_CNT(ws)[0];
    const int mB = WS_CNT(ws)[1];

    float* ob = out;
    float* os = out + N_BOXES * 4;
    float* ol = out + N_BOXES * 5;

    if (k < mA) {
        u64 x = keyA[k];
        int lo = 0, hi = mB;
        while (lo < hi) { int mid = (lo + hi) >> 1; if (keyB[mid] > x) lo = mid + 1; else hi = mid; }
        int pos = k + lo;
        float4 b = boxA[k];
        ob[pos * 4 + 0] = b.x; ob[pos * 4 + 1] = b.y;
        ob[pos * 4 + 2] = b.z; ob[pos * 4 + 3] = b.w;
        os[pos] = __uint_as_float((u32)(x >> 32));
        ol[pos] = 0.0f;
    } else if (k < mA + mB) {
        int i = k - mA;
        u64 x = keyB[i];
        int lo = 0, hi = mA;
        while (lo < hi) { int mid = (lo + hi) >> 1; if (keyA[mid] > x) lo = mid + 1; else hi = mid; }
        int pos = i + lo;
        float4 b = boxB[i];
        ob[pos * 4 + 0] = b.x; ob[pos * 4 + 1] = b.y;
        ob[pos * 4 + 2] = b.z; ob[pos * 4 + 3] = b.w;
        os[pos] = __uint_as_float((u32)(x >> 32));
        ol[pos] = 1.0f;
    } else {
        ob[k * 4 + 0] = 0.0f; ob[k * 4 + 1] = 0.0f;
        ob[k * 4 + 2] = 0.0f; ob[k * 4 + 3] = 0.0f;
        os[k] = 0.0f;
        ol[k] = -1.0f;
    }
}

extern "C" void kernel_launch(void* const* d_in, const int* in_sizes, int n_in,
                              void* d_out, int out_size, void* d_ws, size_t ws_size,
                              hipStream_t stream) {
    const float* boxes  = (const float*)d_in[0];
    const float* scores = (const float*)d_in[1];
    const int*   labels = (const int*)d_in[2];
    float* out = (float*)d_out;
    (void)in_sizes; (void)n_in; (void)out_size; (void)ws_size;
    softnms_class<<<2, T, 0, stream>>>(boxes, scores, labels, d_ws);
    softnms_merge<<<N_BOXES / T, T, 0, stream>>>(d_ws, out);
}

// Round 4
// 4704.670 us; speedup vs baseline: 2.5018x; 1.1823x over previous
//
#include <hip/hip_runtime.h>
#include <stdint.h>

// SoftNMS (gaussian, sigma=0.5, thr=0.001), N=4096, 2 classes.
// R4: three different step implementations all cost ~2.8us/step -> the
// invariant is the per-step GLOBAL STORE (okey/obox) whose vmcnt(0) drain is
// serialized into every step's s_barrier. Changes vs R3:
//  - winner keys staged in LDS (okey_lds); boxes recovered from the LDS box
//    cache by rank at a single batched flush after the loop. Step loop now
//    touches NO global memory -> barrier drains lgkm only.
//  - inter==0 guard: decay=exp(-0)=1.0 exactly -> skip div+expf (bitwise
//    no-op on the score), ~60% of slot-evals at start, more as boxes die.
// Float ops bitwise-identical to R1-R3 (absmax 0.0).

#define N_BOXES 4096
#define T 256
#define CAP 16            // slots/thread capacity (worst case: one class owns all)
#define BOXCAP 2560       // LDS cache capacity (40KB box + 20KB key); cnt>BOXCAP ~8-sigma
#define SCORE_THR 0.001f

typedef unsigned long long u64;
typedef uint32_t u32;

__device__ __forceinline__ u64 kmax(u64 a, u64 b) { return a > b ? a : b; }

// LLVM gfx9 wave64 reduction sequence; identity 0, inputs non-negative.
__device__ __forceinline__ int wave_max_nonneg(int v) {
    v = max(v, __builtin_amdgcn_update_dpp(0, v, 0x111, 0xf, 0xf, false)); // row_shr:1
    v = max(v, __builtin_amdgcn_update_dpp(0, v, 0x112, 0xf, 0xf, false)); // row_shr:2
    v = max(v, __builtin_amdgcn_update_dpp(0, v, 0x114, 0xf, 0xf, false)); // row_shr:4
    v = max(v, __builtin_amdgcn_update_dpp(0, v, 0x118, 0xf, 0xf, false)); // row_shr:8
    v = max(v, __builtin_amdgcn_update_dpp(0, v, 0x142, 0xa, 0xf, false)); // row_bcast:15 -> rows 1,3
    v = max(v, __builtin_amdgcn_update_dpp(0, v, 0x143, 0xc, 0xf, false)); // row_bcast:31 -> rows 2,3
    return __builtin_amdgcn_readlane(v, 63);
}

// workspace layout (196616 bytes)
#define WS_KEY(ws, c)  ((u64*)((char*)(ws) + (size_t)(c) * 32768))
#define WS_BOX(ws, c)  ((float4*)((char*)(ws) + 65536 + (size_t)(c) * 65536))
#define WS_CNT(ws)     ((int*)((char*)(ws) + 196608))

__launch_bounds__(T, 1)
__global__ void softnms_class(const float* __restrict__ boxes,
                              const float* __restrict__ scores,
                              const int* __restrict__ labels,
                              void* __restrict__ ws) {
    const int cls  = blockIdx.x;
    const int tid  = threadIdx.x;
    const int lane = tid & 63;
    const int wid  = tid >> 6;

    __shared__ u64    maskw[64];      // class-membership bitmask
    __shared__ u32    wordpref[64];   // inclusive prefix of popcounts
    __shared__ u64    red[2][4];      // cross-wave argmax slots, double-buffered
    __shared__ float4 box_lds[BOXCAP];
    __shared__ u64    okey_lds[BOXCAP];

    // ---- phase 0a: membership bitmask + popcount prefix ----
    for (int base = 0; base < N_BOXES; base += T) {
        u64 bal = __ballot(labels[base + tid] == cls);
        if (lane == 0) maskw[(base >> 6) + wid] = bal;
    }
    __syncthreads();
    if (wid == 0) {
        u32 v = (u32)__popcll(maskw[lane]);
        #pragma unroll
        for (int d = 1; d < 64; d <<= 1) {
            u32 o = __shfl_up(v, d, 64);
            if (lane >= d) v += o;
        }
        wordpref[lane] = v;
    }
    __syncthreads();
    const int cnt = (int)wordpref[63];

    // ---- phase 0b: rank-select my slots (r = tid + 256*j) -> regs + LDS ----
    float x1r[CAP], y1r[CAP], x2r[CAP], y2r[CAP], ar[CAP];
    u64 key[CAP];
    const float4* boxes4 = reinterpret_cast<const float4*>(boxes);
    #pragma unroll
    for (int j = 0; j < CAP; ++j) {
        key[j] = 0;
        x1r[j] = 0.0f; y1r[j] = 0.0f; x2r[j] = 0.0f; y2r[j] = 0.0f; ar[j] = 0.0f;
        int r = tid + T * j;
        if (r < cnt) {
            int lo = 0, hi = 63;   // smallest word W with wordpref[W] > r
            while (lo < hi) { int mid = (lo + hi) >> 1; if (wordpref[mid] > (u32)r) hi = mid; else lo = mid + 1; }
            int W = lo;
            u32 rb = (W == 0) ? 0u : wordpref[W - 1];
            u32 t = (u32)r - rb;
            u64 x = maskw[W];
            int pos = 0;
            u32 c;
            c = (u32)__popcll(x & 0xFFFFFFFFull); if (t >= c) { pos += 32; t -= c; x >>= 32; }
            c = (u32)__popcll(x & 0xFFFFull);     if (t >= c) { pos += 16; t -= c; x >>= 16; }
            c = (u32)__popcll(x & 0xFFull);       if (t >= c) { pos += 8;  t -= c; x >>= 8; }
            c = (u32)__popcll(x & 0xFull);        if (t >= c) { pos += 4;  t -= c; x >>= 4; }
            c = (u32)__popcll(x & 0x3ull);        if (t >= c) { pos += 2;  t -= c; x >>= 2; }
            c = (u32)__popcll(x & 0x1ull);        if (t >= c) { pos += 1; }
            int g = W * 64 + pos;
            float4 b = boxes4[g];
            x1r[j] = b.x; y1r[j] = b.y; x2r[j] = b.z; y2r[j] = b.w;
            ar[j]  = __fmul_rn(__fsub_rn(b.z, b.x), __fsub_rn(b.w, b.y));
            float s = scores[g];
            // key: score<<32 | (4095-g)<<16 | r   (g: argmax tie-break; r: slot)
            key[j] = ((u64)__float_as_uint(s) << 32)
                   | ((u64)(u32)(4095 - g) << 16) | (u64)(u32)r;
            if (r < BOXCAP) box_lds[r] = b;
        }
    }
    __syncthreads();

    // ---- phase 1: sequential soft-NMS chain over this class ----
    u64*    okey = WS_KEY(ws, cls);
    float4* obox = WS_BOX(ws, cls);
    const bool use_lds = (cnt <= BOXCAP);
    int mcnt = 0;
    int buf  = 0;

    u64 lbest = 0;
    #pragma unroll
    for (int j = 0; j < CAP; ++j) lbest = kmax(lbest, key[j]);

    for (int step = 0; step < cnt; ++step) {
        // exact u64 wave max, two-phase DPP (score bits, then tie-break bits)
        int hi   = (int)(u32)(lbest >> 32);
        int hmax = wave_max_nonneg(hi);
        int lom  = (hi == hmax) ? (int)(u32)lbest : 0;
        int lmax = wave_max_nonneg(lom);
        u64 wbest = ((u64)(u32)hmax << 32) | (u64)(u32)lmax;
        if (lane == 0) red[buf][wid] = wbest;
        __syncthreads();
        u64 w = kmax(kmax(red[buf][0], red[buf][1]), kmax(red[buf][2], red[buf][3]));
        float wscore = __uint_as_float((u32)(w >> 32));
        if (wscore < SCORE_THR) break;   // uniform

        int r = (int)(w & 0xFFFF);
        float4 wb;
        if (use_lds) {
            wb = box_lds[r];                               // broadcast ds_read
            if (tid == 0) okey_lds[mcnt] = w;              // LDS staging only
        } else {
            wb = boxes4[4095 - (int)((w >> 16) & 0xFFFF)]; // fallback
            if (tid == 0) { okey[mcnt] = w; obox[mcnt] = wb; }
        }
        float wx1 = wb.x, wy1 = wb.y, wx2 = wb.z, wy2 = wb.w;
        float warea = __fmul_rn(__fsub_rn(wx2, wx1), __fsub_rn(wy2, wy1));
        mcnt++;

        // decay live boxes; inter==0 -> bitwise no-op, skip div+exp.
        // fused accumulation of next step's local max.
        u64 nb = 0;
        #pragma unroll
        for (int j = 0; j < CAP; ++j) {
            int rr = tid + T * j;
            if (rr < cnt) {
                u64 kj = key[j];
                if (kj != 0) {
                    if (kj == w) {
                        key[j] = 0;
                    } else {
                        float ix1   = fmaxf(wx1, x1r[j]);
                        float iy1   = fmaxf(wy1, y1r[j]);
                        float ix2   = fminf(wx2, x2r[j]);
                        float iy2   = fminf(wy2, y2r[j]);
                        float iw    = fmaxf(__fsub_rn(ix2, ix1), 0.0f);
                        float ih    = fmaxf(__fsub_rn(iy2, iy1), 0.0f);
                        float inter = __fmul_rn(iw, ih);
                        if (inter > 0.0f) {
                            float sc    = __uint_as_float((u32)(kj >> 32));
                            float denom = __fadd_rn(__fsub_rn(__fadd_rn(warea, ar[j]), inter), 1e-8f);
                            float iou   = inter / denom;                // IEEE div
                            float t2    = __fmul_rn(iou, iou);
                            float decay = expf(__fmul_rn(-2.0f, t2));   // exp(-iou^2/0.5)
                            float ns    = __fmul_rn(sc, decay);
                            key[j] = (ns >= SCORE_THR)
                                       ? (((u64)__float_as_uint(ns) << 32) | (kj & 0xFFFFFFFFull))
                                       : 0;
                        }
                    }
                }
                nb = kmax(nb, key[j]);
            }
        }
        lbest = nb;
        buf ^= 1;
    }

    // ---- batched flush of staged winners (boxes recovered by rank) ----
    if (use_lds) {
        __syncthreads();
        for (int m = tid; m < mcnt; m += T) {
            u64 w = okey_lds[m];
            okey[m] = w;
            obox[m] = box_lds[(int)(w & 0xFFFF)];
        }
    }
    if (tid == 0) WS_CNT(ws)[cls] = mcnt;
}

// merge the two strictly-descending key lists by rank; pad the tail
__global__ void softnms_merge(void* __restrict__ ws, float* __restrict__ out) {
    int k = blockIdx.x * blockDim.x + threadIdx.x;   // 0..4095
    const u64*    keyA = WS_KEY(ws, 0);
    const u64*    keyB = WS_KEY(ws, 1);
    const float4* boxA = WS_BOX(ws, 0);
    const float4* boxB = WS_BOX(ws, 1);
    const int mA = WS_CNT(ws)[0];
    const int mB = WS_CNT(ws)[1];

    float* ob = out;
    float* os = out + N_BOXES * 4;
    float* ol = out + N_BOXES * 5;

    if (k < mA) {
        u64 x = keyA[k];
        int lo = 0, hi = mB;
        while (lo < hi) { int mid = (lo + hi) >> 1; if (keyB[mid] > x) lo = mid + 1; else hi = mid; }
        int pos = k + lo;
        float4 b = boxA[k];
        ob[pos * 4 + 0] = b.x; ob[pos * 4 + 1] = b.y;
        ob[pos * 4 + 2] = b.z; ob[pos * 4 + 3] = b.w;
        os[pos] = __uint_as_float((u32)(x >> 32));
        ol[pos] = 0.0f;
    } else if (k < mA + mB) {
        int i = k - mA;
        u64 x = keyB[i];
        int lo = 0, hi = mA;
        while (lo < hi) { int mid = (lo + hi) >> 1; if (keyA[mid] > x) lo = mid + 1; else hi = mid; }
        int pos = i + lo;
        float4 b = boxB[i];
        ob[pos * 4 + 0] = b.x; ob[pos * 4 + 1] = b.y;
        ob[pos * 4 + 2] = b.z; ob[pos * 4 + 3] = b.w;
        os[pos] = __uint_as_float((u32)(x >> 32));
        ol[pos] = 1.0f;
    } else {
        ob[k * 4 + 0] = 0.0f; ob[k * 4 + 1] = 0.0f;
        ob[k * 4 + 2] = 0.0f; ob[k * 4 + 3] = 0.0f;
        os[k] = 0.0f;
        ol[k] = -1.0f;
    }
}

extern "C" void kernel_launch(void* const* d_in, const int* in_sizes, int n_in,
                              void* d_out, int out_size, void* d_ws, size_t ws_size,
                              hipStream_t stream) {
    const float* boxes  = (const float*)d_in[0];
    const float* scores = (const float*)d_in[1];
    const int*   labels = (const int*)d_in[2];
    float* out = (float*)d_out;
    (void)in_sizes; (void)n_in; (void)out_size; (void)ws_size;
    softnms_class<<<2, T, 0, stream>>>(boxes, scores, labels, d_ws);
    softnms_merge<<<N_BOXES / T, T, 0, stream>>>(d_ws, out);
}